// Round 1
// baseline (640.989 us; speedup 1.0000x reference)
//
#include <hip/hip_runtime.h>
#include <hip/hip_fp16.h>

// DynamicRouting (capsule routing), MI355X / gfx950.
// votes: [B=128, I=2048, O=32, P=4] fp32 (128 MiB). activations_in unused.
// b_ij^(t)[b,i,o] = sum_{tau<t} dot(votes[b,i,o,:], v^tau[b,o,:]) -> b_ij never materialized.
//
// R6 changes vs R5 (230.7 us; ~154 us of that is the harness's 2x512MiB ws-poison
// fills, our kernels ~77 us):
//  - single fused kernel: votes held as fp16 IN REGISTERS (64 VGPRs/thread) across
//    all 3 routing iterations -> no 64 MiB fp16 copy write, no 2x64 MiB re-reads.
//  - grid 1024 blocks x 256 thr, __launch_bounds__(256,4) => <=128 VGPR => 4 blk/CU
//    => all 1024 blocks co-resident (256 CU x 4). Cross-iteration dependency only
//    couples the 8 chunk-blocks of one b -> per-b counter barrier (release atomicAdd
//    + acquire spin, agent scope, __threadfence for cross-XCD visibility).
//  - tiny init kernel zeroes the 128 barrier counters (ws is re-poisoned per iter).
// Numerics match R5 (t=0 sum fp32 from original votes; t=1/2 use fp16-rounded votes).

#define BATCH 128
#define IC 2048
#define OC 32
#define POSE 4
#define REPS 1e-7f
#define CHUNKS 8
#define CHUNK_I (IC / CHUNKS)             // 256 input capsules per block
#define BLOCK_T 256
#define GROUPS (BLOCK_T / 32)             // 8 o-groups per block
#define ILP 4
#define STEPS (CHUNK_I / (GROUPS * ILP))  // 8 steps, 4 i's per thread per step
#define SLOTS (STEPS * ILP)               // 32 vote quads per thread (fp16, 64 VGPRs)

// partials layout: [t][b][chunk][o] float4
#define PART_IDX(t, b, c, o) ((((size_t)(t) * BATCH + (b)) * CHUNKS + (c)) * OC + (o))

struct alignas(8) half4v { __half2 xy, zw; };

__device__ __forceinline__ half4v f2h(const float4 v) {
    half4v h;
    h.xy = __float22half2_rn(make_float2(v.x, v.y));
    h.zw = __float22half2_rn(make_float2(v.z, v.w));
    return h;
}
__device__ __forceinline__ float4 h2f(const half4v h) {
    const float2 a = __half22float2(h.xy);
    const float2 b = __half22float2(h.zw);
    return make_float4(a.x, a.y, b.x, b.y);
}

__device__ __forceinline__ float dot4(const float4 a, const float4 b) {
    return a.x*b.x + a.y*b.y + a.z*b.z + a.w*b.w;
}

// squash: v = (n2/(1+n2)) * s / sqrt(n2),  n2 = |s|^2 + eps
__device__ __forceinline__ float4 squash4(const float4 s) {
    const float n2 = s.x*s.x + s.y*s.y + s.z*s.z + s.w*s.w + REPS;
    const float f = n2 / (1.f + n2) * rsqrtf(n2);
    return make_float4(f*s.x, f*s.y, f*s.z, f*s.w);
}

// sum the 8 chunk partials for (b,o) of iteration t, apply scale, squash
__device__ __forceinline__ float4 reduce_squash(
    const float4* __restrict__ partials, int t, int b, int o, float scale)
{
    float4 acc = make_float4(0.f, 0.f, 0.f, 0.f);
    #pragma unroll
    for (int c = 0; c < CHUNKS; ++c) {
        const float4 p = partials[PART_IDX(t, b, c, o)];
        acc.x += p.x; acc.y += p.y; acc.z += p.z; acc.w += p.w;
    }
    acc.x *= scale; acc.y *= scale; acc.z *= scale; acc.w *= scale;
    return squash4(acc);
}

// block-reduce 8 group partials per o, write one chunk partial (no atomics)
__device__ __forceinline__ void block_reduce_store(
    float4 s_acc, float4* lds_s, float4* __restrict__ partials,
    int t, int b, int chunk, int g, int o)
{
    lds_s[g * 32 + o] = s_acc;
    __syncthreads();
    if (threadIdx.x < 32) {
        float4 tot = lds_s[o];
        #pragma unroll
        for (int gg = 1; gg < GROUPS; ++gg) {
            const float4 x = lds_s[gg * 32 + o];
            tot.x += x.x; tot.y += x.y; tot.z += x.z; tot.w += x.w;
        }
        partials[PART_IDX(t, b, chunk, o)] = tot;   // 512 B coalesced
    }
}

// per-b barrier: monotonic counter, 8 arrivals per phase.
// __syncthreads drains this block's partial stores (vmcnt(0) before s_barrier);
// __threadfence writes back L2 (cross-XCD); release add publishes.
__device__ __forceinline__ void bar_arrive(unsigned int* cnt) {
    __syncthreads();
    if (threadIdx.x == 0) {
        __threadfence();
        __hip_atomic_fetch_add(cnt, 1u, __ATOMIC_RELEASE, __HIP_MEMORY_SCOPE_AGENT);
    }
}
__device__ __forceinline__ void bar_wait(unsigned int* cnt, unsigned int target) {
    if (threadIdx.x == 0) {
        while (__hip_atomic_load(cnt, __ATOMIC_ACQUIRE, __HIP_MEMORY_SCOPE_AGENT) < target)
            __builtin_amdgcn_s_sleep(2);
        __threadfence();   // invalidate stale lines before the block reads partials
    }
    __syncthreads();
}

// softmax over o (32 lanes) + weighted accumulate, votes from registers
__device__ __forceinline__ float4 accum_pass(const half4v* __restrict__ hv,
                                             const float4 vh)
{
    float4 s_acc = make_float4(0.f, 0.f, 0.f, 0.f);
    #pragma unroll
    for (int step = 0; step < STEPS; ++step) {
        const float4 v0 = h2f(hv[step * ILP + 0]);
        const float4 v1 = h2f(hv[step * ILP + 1]);
        const float4 v2 = h2f(hv[step * ILP + 2]);
        const float4 v3 = h2f(hv[step * ILP + 3]);

        const float l0 = dot4(v0, vh);
        const float l1 = dot4(v1, vh);
        const float l2 = dot4(v2, vh);
        const float l3 = dot4(v3, vh);
        // no max-subtraction: |logit| <~ 8 (|vh|<2, votes ~ N(0,1)) -> fp32 exp safe
        float e0 = __expf(l0), e1 = __expf(l1), e2 = __expf(l2), e3 = __expf(l3);
        float t0 = e0, t1 = e1, t2 = e2, t3 = e3;
        // butterfly sums over the 32-lane o-group; 4 independent chains interleave
        #pragma unroll
        for (int d = 16; d >= 1; d >>= 1) {
            t0 += __shfl_xor(t0, d);
            t1 += __shfl_xor(t1, d);
            t2 += __shfl_xor(t2, d);
            t3 += __shfl_xor(t3, d);
        }
        const float c0 = e0 * __builtin_amdgcn_rcpf(t0);
        const float c1 = e1 * __builtin_amdgcn_rcpf(t1);
        const float c2 = e2 * __builtin_amdgcn_rcpf(t2);
        const float c3 = e3 * __builtin_amdgcn_rcpf(t3);

        s_acc.x += c0*v0.x + c1*v1.x + c2*v2.x + c3*v3.x;
        s_acc.y += c0*v0.y + c1*v1.y + c2*v2.y + c3*v3.y;
        s_acc.z += c0*v0.z + c1*v1.z + c2*v2.z + c3*v3.z;
        s_acc.w += c0*v0.w + c1*v1.w + c2*v2.w + c3*v3.w;
    }
    return s_acc;
}

__global__ void routing_init(unsigned int* __restrict__ counters) {
    if (threadIdx.x < BATCH) counters[threadIdx.x * 32] = 0;  // one cacheline per b
}

__global__ __launch_bounds__(BLOCK_T, 4) void routing_fused(
    const float4* __restrict__ votes,
    float* __restrict__ out,             // poses [B,O,P] then acts [B,O,1]
    unsigned int* __restrict__ counters,
    float4* __restrict__ partials)
{
    const int blk   = blockIdx.x;
    const int b     = blk >> 3;                 // CHUNKS=8
    const int chunk = blk & (CHUNKS - 1);
    const int o     = threadIdx.x & 31;
    const int g     = threadIdx.x >> 5;
    unsigned int* cnt = counters + (size_t)b * 32;

    __shared__ float4 lds_s[GROUPS * 32];
    __shared__ float4 vh_s[32];

    half4v hv[SLOTS];                           // fp16 votes, register-resident
    const float4* vb = votes + (size_t)b * IC * OC;
    const int i0 = chunk * CHUNK_I;

    // ---- t=0: stream fp32 votes once, keep fp16 in regs, mean-reduce ----
    float4 s_acc = make_float4(0.f, 0.f, 0.f, 0.f);
    #pragma unroll
    for (int step = 0; step < STEPS; ++step) {
        const int ia = i0 + step * (GROUPS * ILP) + g;
        const float4* vp = vb + (size_t)ia * OC + o;
        #pragma unroll
        for (int k = 0; k < ILP; ++k) {
            const float4 v = vp[(size_t)k * GROUPS * OC];   // 1 KiB contiguous/wave
            hv[step * ILP + k] = f2h(v);
            s_acc.x += v.x; s_acc.y += v.y; s_acc.z += v.z; s_acc.w += v.w;
        }
    }
    // softmax(0) == 1/32 uniform; 1/32 applied at the reduce
    block_reduce_store(s_acc, lds_s, partials, 0, b, chunk, g, o);
    bar_arrive(cnt);
    bar_wait(cnt, 1 * CHUNKS);

    // ---- t=1 ----
    if (threadIdx.x < 32)
        vh_s[o] = reduce_squash(partials, 0, b, o, 1.f / 32.f);
    __syncthreads();
    const float4 vh0 = vh_s[o];                 // keep v^0 for t=2 (no re-reduce)

    const float4 s1 = accum_pass(hv, vh0);
    block_reduce_store(s1, lds_s, partials, 1, b, chunk, g, o);
    bar_arrive(cnt);
    bar_wait(cnt, 2 * CHUNKS);

    // ---- t=2: logit = dot(v, vh0) + dot(v, vh1) == dot(v, vh0+vh1) ----
    if (threadIdx.x < 32)
        vh_s[o] = reduce_squash(partials, 1, b, o, 1.f);
    __syncthreads();
    float4 vh01 = vh_s[o];
    vh01.x += vh0.x; vh01.y += vh0.y; vh01.z += vh0.z; vh01.w += vh0.w;

    const float4 s2 = accum_pass(hv, vh01);
    block_reduce_store(s2, lds_s, partials, 2, b, chunk, g, o);
    bar_arrive(cnt);

    // ---- finalize: chunk 0 of each b reduces + writes its 32 outputs ----
    if (chunk == 0) {
        bar_wait(cnt, 3 * CHUNKS);
        if (threadIdx.x < 32) {
            const float4 v = reduce_squash(partials, 2, b, o, 1.f);
            ((float4*)out)[b * OC + o] = v;                            // poses_out
            const float a = sqrtf(v.x*v.x + v.y*v.y + v.z*v.z + v.w*v.w + REPS);
            out[BATCH * OC * POSE + b * OC + o] = a;                   // activations
        }
    }
}

extern "C" void kernel_launch(void* const* d_in, const int* in_sizes, int n_in,
                              void* d_out, int out_size, void* d_ws, size_t ws_size,
                              hipStream_t stream) {
    const float4* votes = (const float4*)d_in[0];
    // d_in[1] (activations_in) unused by the reference.

    // ws layout: counters (16 KiB, one 128B line per b) | partials (1.5 MiB)
    unsigned int* counters = (unsigned int*)d_ws;
    float4* partials = (float4*)((char*)d_ws + 16 * 1024);

    routing_init<<<1, 128, 0, stream>>>(counters);
    routing_fused<<<BATCH * CHUNKS, BLOCK_T, 0, stream>>>(
        votes, (float*)d_out, counters, partials);
}